// Round 9
// baseline (1086.991 us; speedup 1.0000x reference)
//
#include <hip/hip_runtime.h>

#define S_LEN 2048
#define DIN   50
#define H     64

// tanh(v) = 1 - 2/(exp(2v)+1); ~1e-6 rel err, exact at +/-inf
__device__ __forceinline__ float tanh_fast(float v) {
    float e = __builtin_amdgcn_exp2f(v * 2.885390082f);   // exp(2v)
    return 1.0f - 2.0f * __builtin_amdgcn_rcpf(e + 1.0f);
}

// Sum over the four 16-lane groups (every lane ends with the full sum).
// Proven on this toolchain (R3/R6 passed with absmax 0).
__device__ __forceinline__ float red4(float v) {
#if __has_builtin(__builtin_amdgcn_permlane16_swap) && __has_builtin(__builtin_amdgcn_permlane32_swap)
    typedef unsigned u2 __attribute__((ext_vector_type(2)));
    u2 r = __builtin_amdgcn_permlane16_swap(__float_as_uint(v), __float_as_uint(v), false, false);
    float s = __uint_as_float(r[0]) + __uint_as_float(r[1]);
    u2 q = __builtin_amdgcn_permlane32_swap(__float_as_uint(s), __float_as_uint(s), false, false);
    return __uint_as_float(q[0]) + __uint_as_float(q[1]);
#else
    v += __shfl_xor(v, 16, 64);
    v += __shfl_xor(v, 32, 64);
    return v;
#endif
}

__global__ __launch_bounds__(512)
__attribute__((amdgpu_waves_per_eu(4, 4)))   // 4096 waves = exactly 4/EU
void rnn_fused(const float* __restrict__ x,
               const float* __restrict__ W_ih0, const float* __restrict__ W_hh0,
               const float* __restrict__ b_ih0, const float* __restrict__ b_hh0,
               const float* __restrict__ W_ih1, const float* __restrict__ W_hh1,
               const float* __restrict__ b_ih1, const float* __restrict__ b_hh1,
               const float* __restrict__ W1, const float* __restrict__ b1,
               const float* __restrict__ W2, const float* __restrict__ b2,
               float* __restrict__ out)
{
    const int b    = blockIdx.x;
    const int tid  = threadIdx.x;
    const int lane = tid & 63;
    const int w    = __builtin_amdgcn_readfirstlane(tid >> 6);  // 0..7, uniform
    const bool isA = (w < 4);          // A: waves 0-3 compute h1[t]; B: waves 4-7 compute h2[t-1]
    const int wr   = isA ? w : w - 4;  // role-local wave id: outputs [16wr, 16wr+16)
    const int j    = lane & 15;        // output within chunk
    const int kg   = lane >> 4;        // 4-way k-split within wave
    const int outj = 16 * wr + j;

    // Double-buffered state; single barrier per step.
    // h1[t] lives in h1s[t&1]; h2[t] lives in h2s[t&1]; x[t] in xs[t&1].
    __shared__ __align__(16) float xs[2][4][16];   // x row: 13-wide chunks padded to 16
    __shared__ __align__(16) float h1s[2][H];
    __shared__ __align__(16) float h2s[2][H];

    // ---- role-shared weight registers (32 floats) ----
    // A: arrP = W_ih0 chunk (padded), arrQ = W_hh0 chunk
    // B: arrP = W_ih1 chunk,          arrQ = W_hh1 chunk
    float arrP[16], arrQ[16];
    if (isA) {
        #pragma unroll
        for (int i = 0; i < 16; ++i) {
            int c = 13 * kg + i;
            arrP[i] = (i < 13 && c < DIN) ? W_ih0[outj * DIN + c] : 0.0f;
            arrQ[i] = W_hh0[outj * H + 16 * kg + i];
        }
    } else {
        #pragma unroll
        for (int i = 0; i < 16; ++i) {
            arrP[i] = W_ih1[outj * H + 16 * kg + i];
            arrQ[i] = W_hh1[outj * H + 16 * kg + i];
        }
    }
    const float bias = isA ? (b_ih0[outj] + b_hh0[outj])
                           : (b_ih1[outj] + b_hh1[outj]);

    const float* __restrict__ xrow = x + (size_t)b * (size_t)(S_LEN * DIN);

    // x staging (wave 0 only): slot (kg, j) <- x[t*DIN + 13*kg + j]
    const int  scol = 13 * kg + j;
    const bool sval = (tid < 64) && (j < 13) && (scol < DIN);

    if (tid < 64) xs[0][kg][j] = sval ? xrow[scol] : 0.0f;
    float pfA = sval ? xrow[DIN + scol] : 0.0f;        // x[1]
    float pfB = sval ? xrow[2 * DIN + scol] : 0.0f;    // x[2]
    const float* xpf = xrow + 3 * DIN + scol;

    if (tid < 64) { h1s[1][lane] = 0.0f; h2s[1][lane] = 0.0f; }  // h1[-1], h2[-1]
    __syncthreads();

    // One pipeline iteration. A computes h1[t] (t<S_LEN); B computes h2[t-1] (t>=1).
    auto iter = [&](int t, int cur, int prv) {
        if (isA) {
            if (t < S_LEN) {
                float s1[16], s2[16];
                #pragma unroll
                for (int q = 0; q < 4; ++q)
                    *(float4*)&s1[4 * q] = *(const float4*)&xs[cur][kg][4 * q];
                #pragma unroll
                for (int q = 0; q < 4; ++q)
                    *(float4*)&s2[4 * q] = *(const float4*)&h1s[prv][16 * kg + 4 * q];
                float a0 = 0, a1 = 0, a2 = 0, a3 = 0;
                #pragma unroll
                for (int q = 0; q < 4; ++q) {
                    a0 = fmaf(s1[4 * q + 0], arrP[4 * q + 0], a0);
                    a1 = fmaf(s1[4 * q + 1], arrP[4 * q + 1], a1);
                    a2 = fmaf(s1[4 * q + 2], arrP[4 * q + 2], a2);
                    a3 = fmaf(s1[4 * q + 3], arrP[4 * q + 3], a3);
                }
                #pragma unroll
                for (int q = 0; q < 4; ++q) {
                    a0 = fmaf(s2[4 * q + 0], arrQ[4 * q + 0], a0);
                    a1 = fmaf(s2[4 * q + 1], arrQ[4 * q + 1], a1);
                    a2 = fmaf(s2[4 * q + 2], arrQ[4 * q + 2], a2);
                    a3 = fmaf(s2[4 * q + 3], arrQ[4 * q + 3], a3);
                }
                float h1n = tanh_fast(red4((a0 + a1) + (a2 + a3)) + bias);
                if (kg == 0) h1s[cur][outj] = h1n;
                // stage x[t+1] into the other buffer; rotate prefetch
                if (tid < 64) xs[prv][kg][j] = pfA;
                pfA = pfB;
                pfB = (sval && (t + 3) < S_LEN) ? *xpf : 0.0f;
                xpf += DIN;
            }
        } else {
            if (t >= 1) {
                // h1[t-1] in h1s[prv]; h2[t-2] in h2s[cur]; write h2[t-1] -> h2s[prv]
                float s1[16], s2[16];
                #pragma unroll
                for (int q = 0; q < 4; ++q)
                    *(float4*)&s1[4 * q] = *(const float4*)&h1s[prv][16 * kg + 4 * q];
                #pragma unroll
                for (int q = 0; q < 4; ++q)
                    *(float4*)&s2[4 * q] = *(const float4*)&h2s[cur][16 * kg + 4 * q];
                float c0 = 0, c1 = 0, c2 = 0, c3 = 0;
                #pragma unroll
                for (int q = 0; q < 4; ++q) {
                    c0 = fmaf(s1[4 * q + 0], arrP[4 * q + 0], c0);
                    c1 = fmaf(s1[4 * q + 1], arrP[4 * q + 1], c1);
                    c2 = fmaf(s1[4 * q + 2], arrP[4 * q + 2], c2);
                    c3 = fmaf(s1[4 * q + 3], arrP[4 * q + 3], c3);
                }
                #pragma unroll
                for (int q = 0; q < 4; ++q) {
                    c0 = fmaf(s2[4 * q + 0], arrQ[4 * q + 0], c0);
                    c1 = fmaf(s2[4 * q + 1], arrQ[4 * q + 1], c1);
                    c2 = fmaf(s2[4 * q + 2], arrQ[4 * q + 2], c2);
                    c3 = fmaf(s2[4 * q + 3], arrQ[4 * q + 3], c3);
                }
                float h2n = tanh_fast(red4((c0 + c1) + (c2 + c3)) + bias);
                if (kg == 0) h2s[prv][outj] = h2n;
            }
        }
    };

    for (int t = 0; t < S_LEN; t += 2) {
        iter(t, 0, 1);
        __syncthreads();
        iter(t + 1, 1, 0);
        __syncthreads();
    }
    iter(S_LEN, 0, 1);   // drain: B computes h2[S_LEN-1] -> h2s[1]
    __syncthreads();

    // ---- head: relu(h2 @ W1^T + b1) -> sigmoid(. @ W2^T + b2); h2 final in h2s[1] ----
    if (tid < 64) {
        float hv = 0.0f;
        if (lane < 32) {
            float acc = b1[lane];
            #pragma unroll
            for (int k = 0; k < H; ++k)
                acc = fmaf(h2s[1][k], W1[lane * H + k], acc);
            hv = fmaxf(acc, 0.0f) * W2[lane];
        }
        #pragma unroll
        for (int off = 32; off; off >>= 1)
            hv += __shfl_xor(hv, off, 64);
        if (lane == 0)
            out[b] = 1.0f / (1.0f + __expf(-(hv + b2[0])));
    }
}

extern "C" void kernel_launch(void* const* d_in, const int* in_sizes, int n_in,
                              void* d_out, int out_size, void* d_ws, size_t ws_size,
                              hipStream_t stream) {
    const float* x     = (const float*)d_in[0];
    const float* W_ih0 = (const float*)d_in[1];
    const float* W_hh0 = (const float*)d_in[2];
    const float* b_ih0 = (const float*)d_in[3];
    const float* b_hh0 = (const float*)d_in[4];
    const float* W_ih1 = (const float*)d_in[5];
    const float* W_hh1 = (const float*)d_in[6];
    const float* b_ih1 = (const float*)d_in[7];
    const float* b_hh1 = (const float*)d_in[8];
    const float* W1    = (const float*)d_in[9];
    const float* b1    = (const float*)d_in[10];
    const float* W2    = (const float*)d_in[11];
    const float* b2    = (const float*)d_in[12];
    float* out = (float*)d_out;

    rnn_fused<<<dim3(512), dim3(512), 0, stream>>>(
        x, W_ih0, W_hh0, b_ih0, b_hh0,
        W_ih1, W_hh1, b_ih1, b_hh1,
        W1, b1, W2, b2, out);
}

// Round 10
// 1045.497 us; speedup vs baseline: 1.0397x; 1.0397x over previous
//
#include <hip/hip_runtime.h>

#define S_LEN 2048
#define DIN   50
#define H     64
#define XB    32            // steps per x-batch in LDS
#define XEL   (XB * 52)     // padded elements per batch (4 chunks x 13)

// tanh(v) = 1 - 2/(exp(2v)+1); ~1e-6 rel err, exact at +/-inf
__device__ __forceinline__ float tanh_fast(float v) {
    float e = __builtin_amdgcn_exp2f(v * 2.885390082f);   // exp(2v)
    return 1.0f - 2.0f * __builtin_amdgcn_rcpf(e + 1.0f);
}

// Sum over the four 16-lane groups (every lane ends with the full sum).
// Proven on this toolchain (R3/R6/R7 passed with absmax 0).
__device__ __forceinline__ float red4(float v) {
#if __has_builtin(__builtin_amdgcn_permlane16_swap) && __has_builtin(__builtin_amdgcn_permlane32_swap)
    typedef unsigned u2 __attribute__((ext_vector_type(2)));
    u2 r = __builtin_amdgcn_permlane16_swap(__float_as_uint(v), __float_as_uint(v), false, false);
    float s = __uint_as_float(r[0]) + __uint_as_float(r[1]);
    u2 q = __builtin_amdgcn_permlane32_swap(__float_as_uint(s), __float_as_uint(s), false, false);
    return __uint_as_float(q[0]) + __uint_as_float(q[1]);
#else
    v += __shfl_xor(v, 16, 64);
    v += __shfl_xor(v, 32, 64);
    return v;
#endif
}

__global__ __launch_bounds__(256)
__attribute__((amdgpu_waves_per_eu(2, 2)))   // 2048 waves = exactly 2/EU; VGPR budget 256
void rnn_fused(const float* __restrict__ x,
               const float* __restrict__ W_ih0, const float* __restrict__ W_hh0,
               const float* __restrict__ b_ih0, const float* __restrict__ b_hh0,
               const float* __restrict__ W_ih1, const float* __restrict__ W_hh1,
               const float* __restrict__ b_ih1, const float* __restrict__ b_hh1,
               const float* __restrict__ W1, const float* __restrict__ b1,
               const float* __restrict__ W2, const float* __restrict__ b2,
               float* __restrict__ out)
{
    const int b    = blockIdx.x;
    const int tid  = threadIdx.x;
    const int lane = tid & 63;
    const int w    = tid >> 6;      // wave id: outputs [16w, 16w+16)
    const int j    = lane & 15;     // output within chunk
    const int kg   = lane >> 4;     // 4-way k-split within wave
    const int outj = 16 * w + j;

    __shared__ __align__(16) float xb[XB][4][16];   // 8 KB: 32 steps of x, chunk-padded
    __shared__ __align__(16) float h1s[H];
    __shared__ __align__(16) float h2s[H];

    // ---- per-lane weights, register-resident (61 floats) ----
    float wx[13];
    #pragma unroll
    for (int i = 0; i < 13; ++i) {
        int c = 13 * kg + i;
        wx[i] = (c < DIN) ? W_ih0[outj * DIN + c] : 0.0f;
    }
    float whh0_l[16], wih1_l[16], whh1_l[16];
    #pragma unroll
    for (int i = 0; i < 16; ++i) {
        whh0_l[i] = W_hh0[outj * H + 16 * kg + i];
        wih1_l[i] = W_ih1[outj * H + 16 * kg + i];
        whh1_l[i] = W_hh1[outj * H + 16 * kg + i];
    }
    const float bias0 = b_ih0[outj] + b_hh0[outj];
    const float bias1 = b_ih1[outj] + b_hh1[outj];

    const float* __restrict__ xrow = x + (size_t)b * (size_t)(S_LEN * DIN);

    float h1c[16], h2c[16];    // h-state chunk kg in registers
    #pragma unroll
    for (int i = 0; i < 16; ++i) { h1c[i] = 0.0f; h2c[i] = 0.0f; }

    float xacc = 0.0f;

    for (int T = 0; T < S_LEN; T += XB) {
        // ---- refill xb for steps [T, T+XB). All reads of the previous batch
        // completed at the last step's B2; the one HBM stall here amortizes /32.
        #pragma unroll
        for (int r = 0; r < 7; ++r) {
            int f = tid + 256 * r;
            if (f < XEL) {
                int t   = f / 52;
                int rem = f - 52 * t;
                int c   = rem / 13;
                int jj  = rem - 13 * c;
                int col = 13 * c + jj;
                xb[t][c][jj] = (col < DIN) ? xrow[(size_t)(T + t) * DIN + col] : 0.0f;
            }
        }
        __syncthreads();   // refill visible (drains the 7 loads: once per 32 steps)

        // x-projection partial for batch-local step 0
        {
            const float4* xq = (const float4*)&xb[0][kg][0];
            float4 x0 = xq[0], x1 = xq[1], x2 = xq[2];
            float a0 = x0.x * wx[0], a1 = x0.y * wx[1], a2 = x0.z * wx[2], a3 = x0.w * wx[3];
            a0 = fmaf(x1.x, wx[4], a0);  a1 = fmaf(x1.y, wx[5], a1);
            a2 = fmaf(x1.z, wx[6], a2);  a3 = fmaf(x1.w, wx[7], a3);
            a0 = fmaf(x2.x, wx[8], a0);  a1 = fmaf(x2.y, wx[9], a1);
            a2 = fmaf(x2.z, wx[10], a2); a3 = fmaf(x2.w, wx[11], a3);
            a0 = fmaf(xb[0][kg][12], wx[12], a0);
            xacc = (a0 + a1) + (a2 + a3);
        }

        #pragma unroll 2
        for (int u = 0; u < XB; ++u) {
            // ---- stage 1: xacc + whh0-chunk . h1c (old) — registers only ----
            float a0 = xacc, a1 = 0.0f, a2 = 0.0f, a3 = 0.0f;
            #pragma unroll
            for (int q = 0; q < 4; ++q) {
                a0 = fmaf(h1c[4 * q + 0], whh0_l[4 * q + 0], a0);
                a1 = fmaf(h1c[4 * q + 1], whh0_l[4 * q + 1], a1);
                a2 = fmaf(h1c[4 * q + 2], whh0_l[4 * q + 2], a2);
                a3 = fmaf(h1c[4 * q + 3], whh0_l[4 * q + 3], a3);
            }
            float h1n = tanh_fast(red4((a0 + a1) + (a2 + a3)) + bias0);

            // filler: stage-2 h2-part (h2c from prev B2) — independent of h1n
            float c0 = 0.0f, c1 = 0.0f, c2 = 0.0f, c3 = 0.0f;
            #pragma unroll
            for (int q = 0; q < 4; ++q) {
                c0 = fmaf(h2c[4 * q + 0], whh1_l[4 * q + 0], c0);
                c1 = fmaf(h2c[4 * q + 1], whh1_l[4 * q + 1], c1);
                c2 = fmaf(h2c[4 * q + 2], whh1_l[4 * q + 2], c2);
                c3 = fmaf(h2c[4 * q + 3], whh1_l[4 * q + 3], c3);
            }

            if (kg == 0) h1s[outj] = h1n;
            __syncthreads();   // B1: h1_new visible (LDS-only drain)

            // reload h1 chunk in place
            *(float4*)&h1c[0]  = *(const float4*)&h1s[16 * kg + 0];
            *(float4*)&h1c[4]  = *(const float4*)&h1s[16 * kg + 4];
            *(float4*)&h1c[8]  = *(const float4*)&h1s[16 * kg + 8];
            *(float4*)&h1c[12] = *(const float4*)&h1s[16 * kg + 12];

            // x-projection partial for step u+1 (fills h1c ds_read bubble).
            // At u==31 this reads xb[0] (this batch's step-0 row): result is
            // discarded — next batch recomputes xacc after the refill barrier.
            {
                const float4* xq = (const float4*)&xb[(u + 1) & (XB - 1)][kg][0];
                float4 x0 = xq[0], x1 = xq[1], x2 = xq[2];
                float xn0 = x0.x * wx[0], xn1 = x0.y * wx[1], xn2 = x0.z * wx[2], xn3 = x0.w * wx[3];
                xn0 = fmaf(x1.x, wx[4], xn0);  xn1 = fmaf(x1.y, wx[5], xn1);
                xn2 = fmaf(x1.z, wx[6], xn2);  xn3 = fmaf(x1.w, wx[7], xn3);
                xn0 = fmaf(x2.x, wx[8], xn0);  xn1 = fmaf(x2.y, wx[9], xn1);
                xn2 = fmaf(x2.z, wx[10], xn2); xn3 = fmaf(x2.w, wx[11], xn3);
                xn0 = fmaf(xb[(u + 1) & (XB - 1)][kg][12], wx[12], xn0);
                xacc = (xn0 + xn1) + (xn2 + xn3);
            }

            // ---- stage 2: wih1-part on fresh h1c ----
            #pragma unroll
            for (int q = 0; q < 4; ++q) {
                c0 = fmaf(h1c[4 * q + 0], wih1_l[4 * q + 0], c0);
                c1 = fmaf(h1c[4 * q + 1], wih1_l[4 * q + 1], c1);
                c2 = fmaf(h1c[4 * q + 2], wih1_l[4 * q + 2], c2);
                c3 = fmaf(h1c[4 * q + 3], wih1_l[4 * q + 3], c3);
            }
            float h2n = tanh_fast(red4((c0 + c1) + (c2 + c3)) + bias1);

            if (kg == 0) h2s[outj] = h2n;
            __syncthreads();   // B2: h2_new visible (LDS-only drain)

            *(float4*)&h2c[0]  = *(const float4*)&h2s[16 * kg + 0];
            *(float4*)&h2c[4]  = *(const float4*)&h2s[16 * kg + 4];
            *(float4*)&h2c[8]  = *(const float4*)&h2s[16 * kg + 8];
            *(float4*)&h2c[12] = *(const float4*)&h2s[16 * kg + 12];
        }
    }

    // ---- head: relu(h2 @ W1^T + b1) -> sigmoid(. @ W2^T + b2) ----
    if (tid < 64) {
        float hv = 0.0f;
        if (lane < 32) {
            float acc = b1[lane];
            #pragma unroll
            for (int k = 0; k < H; ++k)
                acc = fmaf(h2s[k], W1[lane * H + k], acc);
            hv = fmaxf(acc, 0.0f) * W2[lane];
        }
        #pragma unroll
        for (int off = 32; off; off >>= 1)
            hv += __shfl_xor(hv, off, 64);
        if (lane == 0)
            out[b] = 1.0f / (1.0f + __expf(-(hv + b2[0])));
    }
}

extern "C" void kernel_launch(void* const* d_in, const int* in_sizes, int n_in,
                              void* d_out, int out_size, void* d_ws, size_t ws_size,
                              hipStream_t stream) {
    const float* x     = (const float*)d_in[0];
    const float* W_ih0 = (const float*)d_in[1];
    const float* W_hh0 = (const float*)d_in[2];
    const float* b_ih0 = (const float*)d_in[3];
    const float* b_hh0 = (const float*)d_in[4];
    const float* W_ih1 = (const float*)d_in[5];
    const float* W_hh1 = (const float*)d_in[6];
    const float* b_ih1 = (const float*)d_in[7];
    const float* b_hh1 = (const float*)d_in[8];
    const float* W1    = (const float*)d_in[9];
    const float* b1    = (const float*)d_in[10];
    const float* W2    = (const float*)d_in[11];
    const float* b2    = (const float*)d_in[12];
    float* out = (float*)d_out;

    rnn_fused<<<dim3(512), dim3(256), 0, stream>>>(
        x, W_ih0, W_hh0, b_ih0, b_hh0,
        W_ih1, W_hh1, b_ih1, b_hh1,
        W1, b1, W2, b2, out);
}

// Round 11
// 993.012 us; speedup vs baseline: 1.0946x; 1.0529x over previous
//
#include <hip/hip_runtime.h>

#define S_LEN 2048
#define DIN   50
#define H     64
#define XB    32
#define XPROWS (XB + 1)            // rows T .. T+32 (row 32 = next chunk's row 0)
#define XRPAD  52                  // padded raw x row (52*4B = 208B, 16B-aligned)
#define XRAWN  (XPROWS * XRPAD)    // 1716

// tanh(v) = 1 - 2/(exp(2v)+1); ~1e-6 rel err, exact at +/-inf
__device__ __forceinline__ float tanh_fast(float v) {
    float e = __builtin_amdgcn_exp2f(v * 2.885390082f);   // exp(2v)
    return 1.0f - 2.0f * __builtin_amdgcn_rcpf(e + 1.0f);
}

// Sum over the four 16-lane groups (every lane ends with the full sum).
// Proven on this toolchain (R3..R10 passed with absmax 0).
__device__ __forceinline__ float red4(float v) {
#if __has_builtin(__builtin_amdgcn_permlane16_swap) && __has_builtin(__builtin_amdgcn_permlane32_swap)
    typedef unsigned u2 __attribute__((ext_vector_type(2)));
    u2 r = __builtin_amdgcn_permlane16_swap(__float_as_uint(v), __float_as_uint(v), false, false);
    float s = __uint_as_float(r[0]) + __uint_as_float(r[1]);
    u2 q = __builtin_amdgcn_permlane32_swap(__float_as_uint(s), __float_as_uint(s), false, false);
    return __uint_as_float(q[0]) + __uint_as_float(q[1]);
#else
    v += __shfl_xor(v, 16, 64);
    v += __shfl_xor(v, 32, 64);
    return v;
#endif
}

__global__ __launch_bounds__(256)
__attribute__((amdgpu_waves_per_eu(2, 2)))   // 2048 waves = exactly 2/EU; VGPR budget 256
void rnn_fused(const float* __restrict__ x,
               const float* __restrict__ W_ih0, const float* __restrict__ W_hh0,
               const float* __restrict__ b_ih0, const float* __restrict__ b_hh0,
               const float* __restrict__ W_ih1, const float* __restrict__ W_hh1,
               const float* __restrict__ b_ih1, const float* __restrict__ b_hh1,
               const float* __restrict__ W1, const float* __restrict__ b1,
               const float* __restrict__ W2, const float* __restrict__ b2,
               float* __restrict__ out)
{
    const int b    = blockIdx.x;
    const int tid  = threadIdx.x;
    const int lane = tid & 63;
    const int w    = tid >> 6;      // wave id: outputs [16w, 16w+16)
    const int j    = lane & 15;
    const int kg   = lane >> 4;     // 4-way k-split within wave
    const int outj = 16 * w + j;

    __shared__ __align__(16) float xraw[XRAWN];        // raw x rows, 52-padded
    __shared__ __align__(16) float xp[XPROWS][H];      // x-projection incl. bias0
    __shared__ __align__(16) float h1s[2][H];          // h1[t] in h1s[t&1]
    __shared__ __align__(16) float h2s[2][H];          // h2[t] in h2s[t&1]

    // ---- per-lane weights, register-resident ----
    float wxf[DIN];                                    // W_ih0 row `lane` (refill)
    #pragma unroll
    for (int d = 0; d < DIN; ++d) wxf[d] = W_ih0[lane * DIN + d];
    const float bias0 = b_ih0[lane] + b_hh0[lane];     // folded into xp

    float whh0_l[16], wih1_l[16], whh1_l[16];
    #pragma unroll
    for (int i = 0; i < 16; ++i) {
        whh0_l[i] = W_hh0[outj * H + 16 * kg + i];
        wih1_l[i] = W_ih1[outj * H + 16 * kg + i];
        whh1_l[i] = W_hh1[outj * H + 16 * kg + i];
    }
    const float bias1 = b_ih1[outj] + b_hh1[outj];

    const float* __restrict__ xrow = x + (size_t)b * (size_t)(S_LEN * DIN);

    // ---- refill: stage 33 raw x rows, compute xp[u][h] = W_ih0.x[T+u] + bias0 ----
    auto refill = [&](int T) {
        #pragma unroll
        for (int r = 0; r < 7; ++r) {                  // 7*256 = 1792 >= 1716
            int f = tid + 256 * r;
            if (f < XRAWN) {
                int row = f / XRPAD;
                int col = f - row * XRPAD;
                int t   = T + row;
                float v = 0.0f;
                if (col < DIN && t < S_LEN) v = xrow[(size_t)t * DIN + col];
                xraw[f] = v;
            }
        }
        __syncthreads();                               // xraw visible
        #pragma unroll
        for (int r = 0; r < 9; ++r) {                  // u = w + 4r covers 0..35
            int u = w + 4 * r;
            if (u < XPROWS) {
                const float4* xr4 = (const float4*)&xraw[u * XRPAD];
                float a0 = bias0, a1 = 0.0f;
                #pragma unroll
                for (int q = 0; q < 12; ++q) {
                    float4 v = xr4[q];
                    a0 = fmaf(v.x, wxf[4 * q + 0], a0);
                    a1 = fmaf(v.y, wxf[4 * q + 1], a1);
                    a0 = fmaf(v.z, wxf[4 * q + 2], a0);
                    a1 = fmaf(v.w, wxf[4 * q + 3], a1);
                }
                float2 vt = *(const float2*)&xraw[u * XRPAD + 48];
                a0 = fmaf(vt.x, wxf[48], a0);
                a1 = fmaf(vt.y, wxf[49], a1);
                xp[u][lane] = a0 + a1;                 // thread's h = lane
            }
        }
        __syncthreads();                               // xp visible
    };

    float h1c[16], h2c[16];
    const float* xpp0 = &xp[0][outj];

    // ---- prologue: h1[0] = tanh(xp[0]); h2[-1] = 0 ----
    refill(0);
    {
        float h1n = tanh_fast(xpp0[0]);
        if (kg == 0) h1s[0][outj] = h1n;
        if (tid < 64) h2s[1][lane] = 0.0f;
    }
    __syncthreads();

    // One barrier interval I_t: given h1[t] (h1s[PAR]) and h2[t-1] (h2s[NPAR]),
    // compute h2[t] -> h2s[PAR] and h1[t+1] -> h1s[NPAR].  PAR = t&1 (literal).
    // XPIDX = (t-T)+1: xp row for h1[t+1].  xp is a FULL value: add after red4.
#define INTERVAL(PAR, NPAR, XPIDX)                                             \
    {                                                                          \
        *(float4*)&h1c[0]  = *(const float4*)&h1s[PAR][16 * kg + 0];           \
        *(float4*)&h1c[4]  = *(const float4*)&h1s[PAR][16 * kg + 4];           \
        *(float4*)&h1c[8]  = *(const float4*)&h1s[PAR][16 * kg + 8];           \
        *(float4*)&h1c[12] = *(const float4*)&h1s[PAR][16 * kg + 12];          \
        *(float4*)&h2c[0]  = *(const float4*)&h2s[NPAR][16 * kg + 0];          \
        *(float4*)&h2c[4]  = *(const float4*)&h2s[NPAR][16 * kg + 4];          \
        *(float4*)&h2c[8]  = *(const float4*)&h2s[NPAR][16 * kg + 8];          \
        *(float4*)&h2c[12] = *(const float4*)&h2s[NPAR][16 * kg + 12];         \
        float xpn = xpp0[(XPIDX) * H];                                         \
        /* stage 2: h2[t] = tanh(Wih1.h1[t] + Whh1.h2[t-1] + bias1) */         \
        float c0 = 0, c1 = 0, c2 = 0, c3 = 0;                                  \
        _Pragma("unroll")                                                      \
        for (int q = 0; q < 4; ++q) {                                          \
            c0 = fmaf(h1c[4 * q + 0], wih1_l[4 * q + 0], c0);                  \
            c1 = fmaf(h1c[4 * q + 1], wih1_l[4 * q + 1], c1);                  \
            c2 = fmaf(h1c[4 * q + 2], wih1_l[4 * q + 2], c2);                  \
            c3 = fmaf(h1c[4 * q + 3], wih1_l[4 * q + 3], c3);                  \
        }                                                                      \
        _Pragma("unroll")                                                      \
        for (int q = 0; q < 4; ++q) {                                          \
            c0 = fmaf(h2c[4 * q + 0], whh1_l[4 * q + 0], c0);                  \
            c1 = fmaf(h2c[4 * q + 1], whh1_l[4 * q + 1], c1);                  \
            c2 = fmaf(h2c[4 * q + 2], whh1_l[4 * q + 2], c2);                  \
            c3 = fmaf(h2c[4 * q + 3], whh1_l[4 * q + 3], c3);                  \
        }                                                                      \
        float h2n = tanh_fast(red4((c0 + c1) + (c2 + c3)) + bias1);            \
        /* stage 1: h1[t+1] = tanh(Whh0.h1[t] + xp[t+1]) */                    \
        float a0 = 0, a1 = 0, a2 = 0, a3 = 0;                                  \
        _Pragma("unroll")                                                      \
        for (int q = 0; q < 4; ++q) {                                          \
            a0 = fmaf(h1c[4 * q + 0], whh0_l[4 * q + 0], a0);                  \
            a1 = fmaf(h1c[4 * q + 1], whh0_l[4 * q + 1], a1);                  \
            a2 = fmaf(h1c[4 * q + 2], whh0_l[4 * q + 2], a2);                  \
            a3 = fmaf(h1c[4 * q + 3], whh0_l[4 * q + 3], a3);                  \
        }                                                                      \
        float h1n = tanh_fast(red4((a0 + a1) + (a2 + a3)) + xpn);              \
        if (kg == 0) {                                                         \
            h2s[PAR][outj]  = h2n;                                             \
            h1s[NPAR][outj] = h1n;                                             \
        }                                                                      \
        __syncthreads();                                                       \
    }

    for (int T = 0; T < S_LEN; T += XB) {
        if (T) refill(T);
        #pragma unroll
        for (int ui = 0; ui < XB; ui += 2) {
            INTERVAL(0, 1, ui + 1)       // t = T+ui   (even)
            INTERVAL(1, 0, ui + 2)       // t = T+ui+1 (odd)
        }
    }
#undef INTERVAL
    // (last interval's h1[2048] uses guarded xp[32] of the final chunk: the
    //  loads were zero-guarded, the value is written to h1s[0] and never read)

    // ---- head: relu(h2 @ W1^T + b1) -> sigmoid(. @ W2^T + b2); h2[2047] in h2s[1] ----
    if (tid < 64) {
        float hv = 0.0f;
        if (lane < 32) {
            float acc = b1[lane];
            #pragma unroll
            for (int k = 0; k < H; ++k)
                acc = fmaf(h2s[1][k], W1[lane * H + k], acc);
            hv = fmaxf(acc, 0.0f) * W2[lane];
        }
        #pragma unroll
        for (int off = 32; off; off >>= 1)
            hv += __shfl_xor(hv, off, 64);
        if (lane == 0)
            out[b] = 1.0f / (1.0f + __expf(-(hv + b2[0])));
    }
}

extern "C" void kernel_launch(void* const* d_in, const int* in_sizes, int n_in,
                              void* d_out, int out_size, void* d_ws, size_t ws_size,
                              hipStream_t stream) {
    const float* x     = (const float*)d_in[0];
    const float* W_ih0 = (const float*)d_in[1];
    const float* W_hh0 = (const float*)d_in[2];
    const float* b_ih0 = (const float*)d_in[3];
    const float* b_hh0 = (const float*)d_in[4];
    const float* W_ih1 = (const float*)d_in[5];
    const float* W_hh1 = (const float*)d_in[6];
    const float* b_ih1 = (const float*)d_in[7];
    const float* b_hh1 = (const float*)d_in[8];
    const float* W1    = (const float*)d_in[9];
    const float* b1    = (const float*)d_in[10];
    const float* W2    = (const float*)d_in[11];
    const float* b2    = (const float*)d_in[12];
    float* out = (float*)d_out;

    rnn_fused<<<dim3(512), dim3(256), 0, stream>>>(
        x, W_ih0, W_hh0, b_ih0, b_hh0,
        W_ih1, W_hh1, b_ih1, b_hh1,
        W1, b1, W2, b2, out);
}